// Round 10
// baseline (376.619 us; speedup 1.0000x reference)
//
#include <hip/hip_runtime.h>

#define NXg 4096
#define NYg 4096
#define BROWS 8                 // rows per band
#define ROW0 8                  // band region covers rows [8, 4088)
#define NBANDS 510              // 4080 / BROWS
#define NPANEL 32               // 4096 / CCOLS
#define CCOLS 128               // core cols per block
#define LCOLS 136               // tile cols: 4 halo + 128 + 4 halo
#define TROWS 36                // X3 rows 14 [i0-3..i0+10] + X2 11 [i0-1..i0+9] + X1 11
#define NCHUNK (TROWS * LCOLS / 4)      // 1224 16-byte chunks per tile
#define NJ ((NCHUNK + 63) / 64)         // 20 DMA instructions per wave
#define VPB 32                  // vertical block slots per panel
#define BPB ((NBANDS + VPB - 1) / VPB)  // 16 bands per block (last slot: 14) — always EVEN

static constexpr float C = 10.2375f;    // Z*DT/DX = (1/400)*4095 ; DX==DY

struct F7  { float v[7];  };
struct F10 { float v[10]; };

__device__ __forceinline__ F7 mk7(const float4& a, const float4& b, const float4& c) {
    F7 r;
    r.v[0] = a.w; r.v[1] = b.x; r.v[2] = b.y; r.v[3] = b.z;
    r.v[4] = b.w; r.v[5] = c.x; r.v[6] = c.y;
    return r;
}
__device__ __forceinline__ F10 mk10(const float4& a, const float4& b, const float4& c) {
    F10 r;
    r.v[0] = a.y; r.v[1] = a.z; r.v[2] = a.w;
    r.v[3] = b.x; r.v[4] = b.y; r.v[5] = b.z; r.v[6] = b.w;
    r.v[7] = c.x; r.v[8] = c.y; r.v[9] = c.z;
    return r;
}
__device__ __forceinline__ F7 l7(const float* Lrow, int lc) {
    const float4 a = *(const float4*)(Lrow + lc - 4);
    const float4 b = *(const float4*)(Lrow + lc);
    const float4 c = *(const float4*)(Lrow + lc + 4);
    return mk7(a, b, c);
}
__device__ __forceinline__ F10 l10(const float* Lrow, int lc) {
    const float4 a = *(const float4*)(Lrow + lc - 4);
    const float4 b = *(const float4*)(Lrow + lc);
    const float4 c = *(const float4*)(Lrow + lc + 4);
    return mk10(a, b, c);
}

// async global->LDS, 16B per lane: LDS dest = wave-uniform base + lane*16
__device__ __forceinline__ void gload_lds16(const float* g, float* l) {
    __builtin_amdgcn_global_load_lds(
        (const __attribute__((address_space(1))) void*)g,
        (__attribute__((address_space(3))) void*)l, 16, 0, 0);
}

// ---------------------------------------------------------------------------
// Band kernel: persistent 1-wave blocks, explicit double buffer, counted vmcnt.
// Block = 128-col panel, walks BPB bands of 8 rows. Per band:
//   stage(next band -> other buffer)  [20 global_load_lds]
//   s_waitcnt vmcnt(20)               [waits CURRENT buffer only; next stays
//                                      in flight across the whole compute]
//   compute(current buffer)           [round-9 rolling-window math]
// Single wave => no barriers, no vmcnt(0) drain anywhere in the loop.
// ---------------------------------------------------------------------------
__global__ __launch_bounds__(64) void band_kernel(
    const float* __restrict__ X1, const float* __restrict__ X2,
    const float* __restrict__ X3, const float* __restrict__ w1,
    float* __restrict__ E, float* __restrict__ Hx, float* __restrict__ Hy)
{
    __shared__ float Ba[TROWS * LCOLS];
    __shared__ float Bb[TROWS * LCOLS];

    const int tid  = threadIdx.x;           // 0..63
    const int col0 = blockIdx.x * CCOLS;
    const int k0   = blockIdx.y * BPB;
    const int kend = (k0 + BPB < NBANDS) ? (k0 + BPB) : NBANDS;  // even count

    const float wv = w1[0];
    const float f0 = (wv - 1.0f) / 3.0f;
    const float f1 = -wv;
    const float f2 = wv;
    const float f3 = (1.0f - wv) / 3.0f;

    const int cq = tid & 31;                // col quad 0..31
    const int g  = tid >> 5;                // row group 0..1
    const int lc = 4 + 4 * cq;              // local col of quad start
    const int rb = 4 * g;                   // first output-row offset in band
    const bool gL = (blockIdx.x == 0) && (cq == 0);
    const bool gR = (blockIdx.x == NPANEL - 1) && (cq == 31);

    // ---- stage: DMA one band's X1/X2/X3 ext tile into lbuf (lane-linear) ----
    // Tile layout: rows 0..13 = X3[i0-3 .. i0+10], 14..24 = X2[i0-1 .. i0+9],
    // 25..35 = X1[i0-1 .. i0+9]; each row LCOLS floats = global cols
    // [col0-4, col0+132). Col under/overflow wraps to adjacent rows (in-bounds
    // since grow in [5,4090]); consumed only by lanes overridden by gL/gR.
    auto stage = [&](float* lbuf, int band) {
        const int i0 = ROW0 + band * BROWS;
        #pragma unroll
        for (int j = 0; j < NJ; ++j) {
            const int c = j * 64 + tid;     // chunk index
            if (c < NCHUNK) {
                const int row = c / (LCOLS / 4);
                const int cc  = c - row * (LCOLS / 4);
                const float* base; int grow;
                if (row < 14)      { base = X3; grow = i0 - 3 + row; }
                else if (row < 25) { base = X2; grow = i0 - 15 + row; }
                else               { base = X1; grow = i0 - 26 + row; }
                const float* gp = base + (size_t)grow * NYg + (col0 - 4) + cc * 4;
                gload_lds16(gp, lbuf + (size_t)j * 256);   // uniform base + lane*16
            }
        }
    };

    auto eRow = [&](const F7& x3m2, const F7& x3m1, const F7& x3p0, const F7& x3p1,
                    const F10& x2r, const F7& x1r) -> F7 {
        F7 e;
        #pragma unroll
        for (int m = 0; m < 7; ++m) {
            const float e1 = x1r.v[m] + C * (x3p0.v[m] - x3m1.v[m])
                                      - C * (x2r.v[m + 2] - x2r.v[m + 1]);
            e.v[m] = e1
                + C * (f0 * x3m2.v[m] + f1 * x3m1.v[m] + f2 * x3p0.v[m] + f3 * x3p1.v[m])
                - C * (f0 * x2r.v[m] + f1 * x2r.v[m + 1] + f2 * x2r.v[m + 2] + f3 * x2r.v[m + 3]);
        }
        if (gL) {
            e.v[1] = x1r.v[1];                                  // j=0: copy
            e.v[2] = x1r.v[2] + C * (x3p0.v[2] - x3m1.v[2])
                              - C * (x2r.v[4] - x2r.v[3]);      // j=1: BC only
        }
        if (gR) {
            e.v[4] = x1r.v[4];                                  // j=4095: copy
            e.v[3] = x1r.v[3] + C * (x3p0.v[3] - x3m1.v[3])
                              - C * (x2r.v[5] - x2r.v[4]);      // j=4094: BC only
        }
        return e;
    };

    // ---- compute: one band from LDS tile ----
    auto compute = [&](const float* lb, int band) {
        const int i0 = ROW0 + band * BROWS;
        const float* T3r = lb;                    // X3 rows (idx 0..13)
        const float* T2r = lb + 14 * LCOLS;       // X2 rows (idx 0..10)
        const float* T1r = lb + 25 * LCOLS;       // X1 rows (idx 0..10)
        const int b3 = rb + 3;                    // X3 tile row of global i0+rb
        const int b2 = rb + 1;                    // X2/X1 tile row of global i0+rb

        F7 p3a = l7(&T3r[(b3 - 3) * LCOLS], lc);
        F7 p3b = l7(&T3r[(b3 - 2) * LCOLS], lc);
        F7 p3c = l7(&T3r[(b3 - 1) * LCOLS], lc);
        F7 w3[4];
        w3[0] = l7(&T3r[(b3    ) * LCOLS], lc);
        w3[1] = l7(&T3r[(b3 + 1) * LCOLS], lc);
        w3[2] = l7(&T3r[(b3 + 2) * LCOLS], lc);
        w3[3] = l7(&T3r[(b3 + 3) * LCOLS], lc);

        F10 q2a = l10(&T2r[(b2 - 1) * LCOLS], lc);
        F10 q2b = l10(&T2r[(b2    ) * LCOLS], lc);
        F10 q2c = l10(&T2r[(b2 + 1) * LCOLS], lc);
        F10 w2r = l10(&T2r[(b2 + 2) * LCOLS], lc);

        F7 q1a = l7(&T1r[(b2 - 1) * LCOLS], lc);
        F7 w1r[3];
        w1r[0] = l7(&T1r[(b2    ) * LCOLS], lc);
        w1r[1] = l7(&T1r[(b2 + 1) * LCOLS], lc);
        w1r[2] = l7(&T1r[(b2 + 2) * LCOLS], lc);

        F7 ew[4];                      // E rows (i0+rb)-1 .. +2
        ew[0] = eRow(p3a, p3b, p3c, w3[0], q2a, q1a);
        ew[1] = eRow(p3b, p3c, w3[0], w3[1], q2b, w1r[0]);
        ew[2] = eRow(p3c, w3[0], w3[1], w3[2], q2c, w1r[1]);

        float x2c0[4] = {q2b.v[3], q2b.v[4], q2b.v[5], q2b.v[6]};
        float x2c1[4] = {q2c.v[3], q2c.v[4], q2c.v[5], q2c.v[6]};

        #pragma unroll
        for (int s = 0; s < 4; ++s) {
            const int i = i0 + rb + s;

            ew[3] = eRow(w3[0], w3[1], w3[2], w3[3], w2r, w1r[2]);

            float hx[4], hy[4];
            #pragma unroll
            for (int q = 0; q < 4; ++q) {
                hx[q] = x2c0[q] - C * (w1r[0].v[q + 2] - w1r[0].v[q + 1])
                      - C * (f0 * ew[1].v[q]     + f1 * ew[1].v[q + 1]
                           + f2 * ew[1].v[q + 2] + f3 * ew[1].v[q + 3]);
                hy[q] = w3[0].v[q + 1] + C * (w1r[1].v[q + 1] - w1r[0].v[q + 1])
                      + C * (f0 * ew[0].v[q + 1] + f1 * ew[1].v[q + 1]
                           + f2 * ew[2].v[q + 1] + f3 * ew[3].v[q + 1]);
            }
            if (gL) {
                hx[0] = x2c0[0] - C * (w1r[0].v[2] - w1r[0].v[1]);    // j=0: no f4
                hy[0] = w3[0].v[1];                                   // j=0: copy X3
                hy[1] = w3[0].v[2] + C * (w1r[1].v[2] - w1r[0].v[2]); // j=1: no f4
            }
            if (gR) {
                hx[3] = x2c0[3];                                      // j=4095: copy X2
                hy[3] = w3[0].v[4];                                   // j=4095: copy X3
                hx[2] = x2c0[2] - C * (w1r[0].v[4] - w1r[0].v[3]);    // j=4094: no f4
                hy[2] = w3[0].v[3] + C * (w1r[1].v[3] - w1r[0].v[3]); // j=4094: no f4
            }

            const size_t idx = (size_t)i * NYg + col0 + 4 * cq;
            *(float4*)(E  + idx) = make_float4(ew[1].v[1], ew[1].v[2], ew[1].v[3], ew[1].v[4]);
            *(float4*)(Hx + idx) = make_float4(hx[0], hx[1], hx[2], hx[3]);
            *(float4*)(Hy + idx) = make_float4(hy[0], hy[1], hy[2], hy[3]);

            ew[0] = ew[1]; ew[1] = ew[2]; ew[2] = ew[3];
            w3[0] = w3[1]; w3[1] = w3[2]; w3[2] = w3[3];
            w1r[0] = w1r[1]; w1r[1] = w1r[2];
            #pragma unroll
            for (int q = 0; q < 4; ++q) { x2c0[q] = x2c1[q]; x2c1[q] = w2r.v[3 + q]; }
            if (s < 3) {
                w3[3]  = l7 (&T3r[(b3 + 4 + s) * LCOLS], lc);   // X3 row i+4 (<=13)
                w2r    = l10(&T2r[(b2 + 3 + s) * LCOLS], lc);   // X2 row i+3 (<=10)
                w1r[2] = l7 (&T1r[(b2 + 3 + s) * LCOLS], lc);   // X1 row i+3 (<=10)
            }
        }
    };

    // ---- pipeline: 2x-unrolled (band count per block is always even) ----
    stage(Ba, k0);
    for (int k = k0; k < kend; k += 2) {
        stage(Bb, k + 1);
        asm volatile("s_waitcnt vmcnt(20)" ::: "memory");   // Ba ready; Bb in flight
        compute(Ba, k);
        if (k + 2 < kend) {
            stage(Ba, k + 2);
            asm volatile("s_waitcnt vmcnt(20)" ::: "memory"); // Bb ready; Ba in flight
        } else {
            asm volatile("s_waitcnt vmcnt(0)" ::: "memory");  // last pair: drain
        }
        compute(Bb, k + 1);
    }
}

// ---------------------------------------------------------------------------
// Edge kernel: boundary row bands [0,7] and [4088,4095], fully guarded.
// ---------------------------------------------------------------------------
#define TRE 8
#define EROWSE 12
#define ECOLSE 136

__global__ __launch_bounds__(256) void edge_kernel(
    const float* __restrict__ X1, const float* __restrict__ X2,
    const float* __restrict__ X3, const float* __restrict__ w1,
    float* __restrict__ E, float* __restrict__ Hx, float* __restrict__ Hy)
{
    __shared__ float elds[EROWSE][ECOLSE];
    const int t    = threadIdx.x;
    const int row0 = blockIdx.y ? (NXg - TRE) : 0;
    const int col0 = blockIdx.x * 128;

    const float wv = w1[0];
    const float f0 = (wv - 1.0f) / 3.0f;
    const float f1 = -wv;
    const float f2 = wv;
    const float f3 = (1.0f - wv) / 3.0f;

    for (int cidx = t; cidx < EROWSE * ECOLSE; cidx += 256) {
        const int r  = cidx / ECOLSE;
        const int cc = cidx - r * ECOLSE;
        const int gr = row0 - 2 + r;
        const int gc = col0 - 4 + cc;
        float e = 0.0f;
        if (gr >= 0 && gr < NXg && gc >= 0 && gc < NYg) {
            const size_t idx = (size_t)gr * NYg + gc;
            const float x1 = X1[idx];
            if (gr == 0 || gr == NXg - 1 || gc == 0 || gc == NYg - 1) {
                e = x1;
            } else {
                float e1 = x1 + C * (X3[idx] - X3[idx - NYg])
                              - C * (X2[idx] - X2[idx - 1]);
                if (gr >= 2 && gr <= NXg - 3 && gc >= 2 && gc <= NYg - 3) {
                    e1 += C * (f0 * X3[idx - 2 * NYg] + f1 * X3[idx - NYg]
                             + f2 * X3[idx] + f3 * X3[idx + NYg])
                        - C * (f0 * X2[idx - 2] + f1 * X2[idx - 1]
                             + f2 * X2[idx] + f3 * X2[idx + 1]);
                }
                e = e1;
            }
        }
        elds[r][cc] = e;
    }
    __syncthreads();

    for (int cidx = t; cidx < TRE * 128; cidx += 256) {
        const int hr  = cidx >> 7;
        const int tc  = cidx & 127;
        const int gr  = row0 + hr;
        const int gcc = col0 + tc;
        const size_t idx = (size_t)gr * NYg + gcc;
        const int lr  = hr + 2;
        const int lc2 = tc + 4;

        const float ec = elds[lr][lc2];
        E[idx] = ec;

        const float x1 = X1[idx];

        float hx = X2[idx];
        if (gr >= 1 && gr <= NXg - 2 && gcc <= NYg - 2)
            hx -= C * (X1[idx + 1] - x1);
        if (gr >= 2 && gr <= NXg - 3 && gcc >= 1 && gcc <= NYg - 3) {
            hx -= C * (f0 * elds[lr][lc2 - 1] + f1 * ec
                     + f2 * elds[lr][lc2 + 1] + f3 * elds[lr][lc2 + 2]);
        }
        Hx[idx] = hx;

        float hy = X3[idx];
        if (gr <= NXg - 2 && gcc >= 1 && gcc <= NYg - 2)
            hy += C * (X1[idx + NYg] - x1);
        if (gr >= 1 && gr <= NXg - 3 && gcc >= 2 && gcc <= NYg - 3) {
            hy += C * (f0 * elds[lr - 1][lc2] + f1 * ec
                     + f2 * elds[lr + 1][lc2] + f3 * elds[lr + 2][lc2]);
        }
        Hy[idx] = hy;
    }
}

extern "C" void kernel_launch(void* const* d_in, const int* in_sizes, int n_in,
                              void* d_out, int out_size, void* d_ws, size_t ws_size,
                              hipStream_t stream) {
    const float* X1 = (const float*)d_in[0];
    const float* X2 = (const float*)d_in[1];
    const float* X3 = (const float*)d_in[2];
    const float* w1 = (const float*)d_in[3];

    float* E  = (float*)d_out;
    float* Hx = (float*)d_out + (size_t)NXg * NYg;
    float* Hy = (float*)d_out + 2 * (size_t)NXg * NYg;

    // edge first: its 64 small blocks finish before band's persistent blocks
    // fill every CU slot (band grid = 1024 = exactly 4 blocks/CU).
    edge_kernel<<<dim3(32, 2), 256, 0, stream>>>(X1, X2, X3, w1, E, Hx, Hy);
    band_kernel<<<dim3(NPANEL, VPB), 64, 0, stream>>>(X1, X2, X3, w1, E, Hx, Hy);
}

// Round 11
// 169.690 us; speedup vs baseline: 2.2195x; 2.2195x over previous
//
#include <hip/hip_runtime.h>

#define NXg 4096
#define NYg 4096
#define BROWS 8                 // rows per band
#define ROW0 8                  // band region covers rows [8, 4088)
#define NBANDS 510
#define NPANEL 32               // 4096 / CCOLS
#define CCOLS 128               // core cols per block
#define LCOLS 136               // 4 halo + 128 + 4 halo
#define CPR 34                  // 16B chunks per tile row (LCOLS/4)
#define NCHUNK 1224             // 36 rows * 34 chunks
#define NJ 5                    // DMA instrs per wave per stage (5*4*64 = 1280 >= 1224)
#define VPB 30                  // vertical block slots
#define BPB 17                  // bands per block: 30*17 = 510 exactly

static constexpr float C = 10.2375f;    // Z*DT/DX = (1/400)*4095 ; DX==DY

struct F4  { float v[4];  };
struct F7  { float v[7];  };
struct F10 { float v[10]; };

__device__ __forceinline__ F4 lb4(const float* Lrow, int lc) {
    const float4 b = *(const float4*)(Lrow + lc);
    F4 x; x.v[0] = b.x; x.v[1] = b.y; x.v[2] = b.z; x.v[3] = b.w;
    return x;
}
__device__ __forceinline__ F7 l7(const float* Lrow, int lc) {
    const float4 a = *(const float4*)(Lrow + lc - 4);
    const float4 b = *(const float4*)(Lrow + lc);
    const float4 c = *(const float4*)(Lrow + lc + 4);
    F7 x;
    x.v[0] = a.w; x.v[1] = b.x; x.v[2] = b.y; x.v[3] = b.z;
    x.v[4] = b.w; x.v[5] = c.x; x.v[6] = c.y;
    return x;
}
__device__ __forceinline__ F10 l10(const float* Lrow, int lc) {
    const float4 a = *(const float4*)(Lrow + lc - 4);
    const float4 b = *(const float4*)(Lrow + lc);
    const float4 c = *(const float4*)(Lrow + lc + 4);
    F10 x;
    x.v[0] = a.y; x.v[1] = a.z; x.v[2] = a.w;
    x.v[3] = b.x; x.v[4] = b.y; x.v[5] = b.z; x.v[6] = b.w;
    x.v[7] = c.x; x.v[8] = c.y; x.v[9] = c.z;
    return x;
}
__device__ __forceinline__ F4 mid(const F7& s) {
    F4 x; x.v[0] = s.v[1]; x.v[1] = s.v[2]; x.v[2] = s.v[3]; x.v[3] = s.v[4];
    return x;
}

// ---------------------------------------------------------------------------
// Band kernel: 4-wave blocks, double-buffered DMA, counted vmcnt, raw barriers.
// Per band: stage(next->other buf) [exactly 5 global_load_lds per wave] ->
// vmcnt(5) [cur's DMAs done, next's in flight] -> s_barrier -> compute(cur)
// [round-7 straight-line math, 33 ds_read_b128/thread] -> s_barrier -> swap.
// 960 blocks co-resident (4/CU, 16 waves/CU) walk 17 bands each.
// ---------------------------------------------------------------------------
__global__ __launch_bounds__(256, 4) void band_kernel(
    const float* __restrict__ X1, const float* __restrict__ X2,
    const float* __restrict__ X3, const float* __restrict__ w1,
    float* __restrict__ E, float* __restrict__ Hx, float* __restrict__ Hy)
{
    __shared__ float Ba[NJ * 1024];     // 20480 B
    __shared__ float Bb[NJ * 1024];

    const int tid  = threadIdx.x;           // 0..255
    const int col0 = blockIdx.x * CCOLS;
    const int k0   = blockIdx.y * BPB;

    const float wv = w1[0];
    const float f0 = (wv - 1.0f) / 3.0f;
    const float f1 = -wv;
    const float f2 = wv;
    const float f3 = (1.0f - wv) / 3.0f;

    const int cq = tid & 31;                // col quad 0..31
    const int g  = tid >> 5;                // row in band 0..7
    const int lc = 4 + 4 * cq;
    const bool gL = (blockIdx.x == 0) && (cq == 0);
    const bool gR = (blockIdx.x == NPANEL - 1) && (cq == 31);

    // ---- stage: flat DMA of one band's tile (X3 rows 0..13 = i0-3..i0+10,
    // X2 rows 14..24 = i0-1..i0+9, X1 rows 25..35). Branchless region select
    // so every wave issues exactly NJ instructions (vmcnt count is exact).
    // Clamped chunks (1224..1279) write duplicate data into unused slots.
    auto stage = [&](float* lbuf, int band) {
        const int i0b = ROW0 + band * BROWS;
        #pragma unroll
        for (int j = 0; j < NJ; ++j) {
            const int c   = j * 256 + tid;
            const int cc2 = (c < NCHUNK) ? c : (NCHUNK - 1);
            const int row = cc2 / CPR;
            const int col4 = cc2 - row * CPR;
            const float* base = (row < 14) ? X3 : ((row < 25) ? X2 : X1);
            const int grow = i0b + ((row < 14) ? (row - 3)
                                 : ((row < 25) ? (row - 15) : (row - 26)));
            const float* gp = base + (size_t)grow * NYg + (col0 - 4) + col4 * 4;
            float* lp = lbuf + j * 1024 + (tid >> 6) * 256;   // wave-uniform base
            __builtin_amdgcn_global_load_lds(
                (const __attribute__((address_space(1))) void*)gp,
                (__attribute__((address_space(3))) void*)lp, 16, 0, 0);
        }
    };

    auto eRow4 = [&](const F4& a, const F4& b, const F4& cc, const F4& d,
                     const F10& x2r, const F4& x1r) -> F4 {
        F4 e;
        #pragma unroll
        for (int q = 0; q < 4; ++q) {
            const float e1 = x1r.v[q] + C * (cc.v[q] - b.v[q])
                                      - C * (x2r.v[q + 3] - x2r.v[q + 2]);
            e.v[q] = e1
                + C * (f0 * a.v[q] + f1 * b.v[q] + f2 * cc.v[q] + f3 * d.v[q])
                - C * (f0 * x2r.v[q + 1] + f1 * x2r.v[q + 2]
                     + f2 * x2r.v[q + 3] + f3 * x2r.v[q + 4]);
        }
        if (gL) {
            e.v[0] = x1r.v[0];
            e.v[1] = x1r.v[1] + C * (cc.v[1] - b.v[1])
                              - C * (x2r.v[4] - x2r.v[3]);
        }
        if (gR) {
            e.v[3] = x1r.v[3];
            e.v[2] = x1r.v[2] + C * (cc.v[2] - b.v[2])
                              - C * (x2r.v[5] - x2r.v[4]);
        }
        return e;
    };

    // ---- compute: one band, 1 row/thread, straight-line (round-7 math) ----
    auto compute = [&](const float* lb, int band) {
        const int i0b = ROW0 + band * BROWS;
        const int i   = i0b + g;
        const float* T3 = lb;
        const float* T2 = lb + 14 * LCOLS;
        const float* T1 = lb + 25 * LCOLS;

        const F4  x3m3 = lb4(&T3[(g    ) * LCOLS], lc);
        const F7  x3m2 = l7 (&T3[(g + 1) * LCOLS], lc);
        const F7  x3m1 = l7 (&T3[(g + 2) * LCOLS], lc);
        const F7  x3i  = l7 (&T3[(g + 3) * LCOLS], lc);
        const F7  x3p1 = l7 (&T3[(g + 4) * LCOLS], lc);
        const F4  x3p2 = lb4(&T3[(g + 5) * LCOLS], lc);
        const F4  x3p3 = lb4(&T3[(g + 6) * LCOLS], lc);

        const F10 x2m1 = l10(&T2[(g    ) * LCOLS], lc);
        const F10 x2i  = l10(&T2[(g + 1) * LCOLS], lc);
        const F10 x2p1 = l10(&T2[(g + 2) * LCOLS], lc);
        const F10 x2p2 = l10(&T2[(g + 3) * LCOLS], lc);

        const F4  x1m1 = lb4(&T1[(g    ) * LCOLS], lc);
        const F7  x1i  = l7 (&T1[(g + 1) * LCOLS], lc);
        const F4  x1p1 = lb4(&T1[(g + 2) * LCOLS], lc);
        const F4  x1p2 = lb4(&T1[(g + 3) * LCOLS], lc);

        // E row i, 7-wide
        F7 e7;
        #pragma unroll
        for (int m = 0; m < 7; ++m) {
            const float e1 = x1i.v[m] + C * (x3i.v[m] - x3m1.v[m])
                                      - C * (x2i.v[m + 2] - x2i.v[m + 1]);
            e7.v[m] = e1
                + C * (f0 * x3m2.v[m] + f1 * x3m1.v[m] + f2 * x3i.v[m] + f3 * x3p1.v[m])
                - C * (f0 * x2i.v[m] + f1 * x2i.v[m + 1] + f2 * x2i.v[m + 2] + f3 * x2i.v[m + 3]);
        }
        if (gL) {
            e7.v[1] = x1i.v[1];
            e7.v[2] = x1i.v[2] + C * (x3i.v[2] - x3m1.v[2])
                               - C * (x2i.v[4] - x2i.v[3]);
        }
        if (gR) {
            e7.v[4] = x1i.v[4];
            e7.v[3] = x1i.v[3] + C * (x3i.v[3] - x3m1.v[3])
                               - C * (x2i.v[5] - x2i.v[4]);
        }

        const F4 em1 = eRow4(x3m3,      mid(x3m2), mid(x3m1), mid(x3i), x2m1, x1m1);
        const F4 ep1 = eRow4(mid(x3m1), mid(x3i),  mid(x3p1), x3p2,     x2p1, x1p1);
        const F4 ep2 = eRow4(mid(x3i),  mid(x3p1), x3p2,      x3p3,     x2p2, x1p2);

        float hx[4], hy[4];
        #pragma unroll
        for (int q = 0; q < 4; ++q) {
            hx[q] = x2i.v[q + 3] - C * (x1i.v[q + 2] - x1i.v[q + 1])
                  - C * (f0 * e7.v[q] + f1 * e7.v[q + 1]
                       + f2 * e7.v[q + 2] + f3 * e7.v[q + 3]);
            hy[q] = x3i.v[q + 1] + C * (x1p1.v[q] - x1i.v[q + 1])
                  + C * (f0 * em1.v[q] + f1 * e7.v[q + 1]
                       + f2 * ep1.v[q] + f3 * ep2.v[q]);
        }
        if (gL) {
            hx[0] = x2i.v[3] - C * (x1i.v[2] - x1i.v[1]);
            hy[0] = x3i.v[1];
            hy[1] = x3i.v[2] + C * (x1p1.v[1] - x1i.v[2]);
        }
        if (gR) {
            hx[3] = x2i.v[6];
            hy[3] = x3i.v[4];
            hx[2] = x2i.v[5] - C * (x1i.v[4] - x1i.v[3]);
            hy[2] = x3i.v[3] + C * (x1p1.v[2] - x1i.v[3]);
        }

        const size_t idx = (size_t)i * NYg + col0 + 4 * cq;
        *(float4*)(E  + idx) = make_float4(e7.v[1], e7.v[2], e7.v[3], e7.v[4]);
        *(float4*)(Hx + idx) = make_float4(hx[0], hx[1], hx[2], hx[3]);
        *(float4*)(Hy + idx) = make_float4(hy[0], hy[1], hy[2], hy[3]);
    };

    // ---- pipeline ----
    float* cur = Ba;
    float* nxt = Bb;
    stage(cur, k0);
    for (int k = k0; k < k0 + BPB; ++k) {
        if (k + 1 < k0 + BPB) {
            stage(nxt, k + 1);
            asm volatile("s_waitcnt vmcnt(5)" ::: "memory");  // cur ready; nxt in flight
        } else {
            asm volatile("s_waitcnt vmcnt(0)" ::: "memory");  // last band: drain
        }
        __builtin_amdgcn_s_barrier();        // all waves' cur-chunks resident
        compute(cur, k);
        asm volatile("" ::: "memory");
        __builtin_amdgcn_s_barrier();        // all reads of cur done before restage
        float* tmp = cur; cur = nxt; nxt = tmp;
    }
}

// ---------------------------------------------------------------------------
// Edge kernel: boundary row bands [0,7] and [4088,4095], fully guarded.
// ---------------------------------------------------------------------------
#define TRE 8
#define EROWSE 12
#define ECOLSE 136

__global__ __launch_bounds__(256) void edge_kernel(
    const float* __restrict__ X1, const float* __restrict__ X2,
    const float* __restrict__ X3, const float* __restrict__ w1,
    float* __restrict__ E, float* __restrict__ Hx, float* __restrict__ Hy)
{
    __shared__ float elds[EROWSE][ECOLSE];
    const int t    = threadIdx.x;
    const int row0 = blockIdx.y ? (NXg - TRE) : 0;
    const int col0 = blockIdx.x * 128;

    const float wv = w1[0];
    const float f0 = (wv - 1.0f) / 3.0f;
    const float f1 = -wv;
    const float f2 = wv;
    const float f3 = (1.0f - wv) / 3.0f;

    for (int cidx = t; cidx < EROWSE * ECOLSE; cidx += 256) {
        const int r  = cidx / ECOLSE;
        const int cc = cidx - r * ECOLSE;
        const int gr = row0 - 2 + r;
        const int gc = col0 - 4 + cc;
        float e = 0.0f;
        if (gr >= 0 && gr < NXg && gc >= 0 && gc < NYg) {
            const size_t idx = (size_t)gr * NYg + gc;
            const float x1 = X1[idx];
            if (gr == 0 || gr == NXg - 1 || gc == 0 || gc == NYg - 1) {
                e = x1;
            } else {
                float e1 = x1 + C * (X3[idx] - X3[idx - NYg])
                              - C * (X2[idx] - X2[idx - 1]);
                if (gr >= 2 && gr <= NXg - 3 && gc >= 2 && gc <= NYg - 3) {
                    e1 += C * (f0 * X3[idx - 2 * NYg] + f1 * X3[idx - NYg]
                             + f2 * X3[idx] + f3 * X3[idx + NYg])
                        - C * (f0 * X2[idx - 2] + f1 * X2[idx - 1]
                             + f2 * X2[idx] + f3 * X2[idx + 1]);
                }
                e = e1;
            }
        }
        elds[r][cc] = e;
    }
    __syncthreads();

    for (int cidx = t; cidx < TRE * 128; cidx += 256) {
        const int hr  = cidx >> 7;
        const int tc  = cidx & 127;
        const int gr  = row0 + hr;
        const int gcc = col0 + tc;
        const size_t idx = (size_t)gr * NYg + gcc;
        const int lr  = hr + 2;
        const int lc2 = tc + 4;

        const float ec = elds[lr][lc2];
        E[idx] = ec;

        const float x1 = X1[idx];

        float hx = X2[idx];
        if (gr >= 1 && gr <= NXg - 2 && gcc <= NYg - 2)
            hx -= C * (X1[idx + 1] - x1);
        if (gr >= 2 && gr <= NXg - 3 && gcc >= 1 && gcc <= NYg - 3) {
            hx -= C * (f0 * elds[lr][lc2 - 1] + f1 * ec
                     + f2 * elds[lr][lc2 + 1] + f3 * elds[lr][lc2 + 2]);
        }
        Hx[idx] = hx;

        float hy = X3[idx];
        if (gr <= NXg - 2 && gcc >= 1 && gcc <= NYg - 2)
            hy += C * (X1[idx + NYg] - x1);
        if (gr >= 1 && gr <= NXg - 3 && gcc >= 2 && gcc <= NYg - 3) {
            hy += C * (f0 * elds[lr - 1][lc2] + f1 * ec
                     + f2 * elds[lr + 1][lc2] + f3 * elds[lr + 2][lc2]);
        }
        Hy[idx] = hy;
    }
}

extern "C" void kernel_launch(void* const* d_in, const int* in_sizes, int n_in,
                              void* d_out, int out_size, void* d_ws, size_t ws_size,
                              hipStream_t stream) {
    const float* X1 = (const float*)d_in[0];
    const float* X2 = (const float*)d_in[1];
    const float* X3 = (const float*)d_in[2];
    const float* w1 = (const float*)d_in[3];

    float* E  = (float*)d_out;
    float* Hx = (float*)d_out + (size_t)NXg * NYg;
    float* Hy = (float*)d_out + 2 * (size_t)NXg * NYg;

    edge_kernel<<<dim3(32, 2), 256, 0, stream>>>(X1, X2, X3, w1, E, Hx, Hy);
    band_kernel<<<dim3(NPANEL, VPB), 256, 0, stream>>>(X1, X2, X3, w1, E, Hx, Hy);
}